// Round 10
// baseline (255.525 us; speedup 1.0000x reference)
//
#include <hip/hip_runtime.h>

#define NBATCH 32
#define SEQ    2048
#define NU     512

typedef __attribute__((ext_vector_type(8))) short bf16x8;
typedef __attribute__((ext_vector_type(4))) float f32x4;

__device__ __forceinline__ short bf16_rne(float f) {
  union { float f; unsigned u; } v; v.f = f;
  unsigned r = v.u + 0x7fffu + ((v.u >> 16) & 1u);
  return (short)(r >> 16);
}

// pack bf16(lo), bf16(hi) (truncation) into one u32 via a single v_perm_b32
__device__ __forceinline__ unsigned pk2(float lo, float hi) {
  return __builtin_amdgcn_perm(__float_as_uint(hi), __float_as_uint(lo), 0x07060302u);
}

__device__ __forceinline__ float fast_tanh(float x) {
  float ax = __builtin_fabsf(x);
  float t  = __expf(-2.0f * ax);
  float r  = (1.0f - t) / (1.0f + t);
  return x < 0.0f ? -r : r;
}

// ---------- fused prep ----------
// blocks 0..1023: WtSw[col*512 + j] = bf16(W[j ^ ((col&7)<<3)][col])
// blocks 1024..1087: first[b][u] = s_prev[b]@U + U_bias + W_bias
__global__ __launch_bounds__(256) void prep_all(const float* __restrict__ W,
                                                const float* __restrict__ sp,
                                                const float* __restrict__ U,
                                                const float* __restrict__ Ub,
                                                const float* __restrict__ Wb,
                                                short* __restrict__ WtSw,
                                                float* __restrict__ first) {
  __shared__ float srow[NU];
  if (blockIdx.x < 1024) {
    int idx = blockIdx.x * 256 + threadIdx.x;
    int col = idx >> 9, j = idx & 511;
    int ksrc = j ^ ((col & 7) << 3);
    WtSw[idx] = bf16_rne(W[(size_t)ksrc * NU + col]);
  } else {
    int blk = blockIdx.x - 1024;
    int b = blk >> 1, half = blk & 1, t = threadIdx.x;
    srow[t]       = sp[b * NU + t];
    srow[t + 256] = sp[b * NU + t + 256];
    __syncthreads();
    int col = half * 256 + t;
    float acc = Ub[col] + Wb[col];
    #pragma unroll 8
    for (int k = 0; k < NU; ++k) acc += srow[k] * U[(size_t)k * NU + col];
    first[b * NU + col] = acc;
  }
}

// ---------- main: W-stationary LDS, barrier-free, explicit load pipeline ----------
// Same structure as R9 (passed, 122us) but the inner loop software-pipelines the
// 8 h-loads: named g0..g7 slots, consumed by CVT(kt) then immediately re-issued
// for kt+1 -> issue-to-use distance = one full iteration of ds_read+MFMA.
__global__ __launch_bounds__(512, 2) void attn_main(
    const float* __restrict__ h,      // (65536, 512) fp32
    const short* __restrict__ WtSw,   // pre-swizzled (512 cols x 512 k) bf16
    const float* __restrict__ first,  // (B, 512) incl. U_bias + W_bias
    const float* __restrict__ V,      // (512)
    float* __restrict__ s0)           // (65536) score accumulator (pre-zeroed)
{
  __shared__ short Wlds[128 * NU];    // 128 KB

  const int tid  = threadIdx.x;
  const int lane = tid & 63;
  const int w    = tid >> 6;          // 0..7
  const int lr   = lane & 15, lg = lane >> 4;

  const int bid = blockIdx.x;
  const int cg  = bid >> 6;           // 128-col group (0..3)
  const int blk = bid & 63;           // 1024-row block; XCD = blk%8 (shared by 4 cgs)

  // ---- stage the block's W slice once (linear copy, coalesced)
  {
    const short* src = WtSw + (size_t)cg * 128 * NU;
    #pragma unroll
    for (int i = 0; i < 16; ++i) {
      int o = i * 4096 + tid * 8;
      *reinterpret_cast<uint4*>(&Wlds[o]) = *reinterpret_cast<const uint4*>(src + o);
    }
  }
  __syncthreads();

  const int swz = (lr & 7) << 4;                // byte XOR within W row
  const char* wbytes = reinterpret_cast<const char*>(Wlds);
  const int b0 = blk >> 1;                      // batch

  const int prow0 = blk * 1024 + w * 128;       // this wave's first panel row
  const float* hb = h + (size_t)(prow0 + lr) * NU + lg * 8;

  float4 g0, g1, g2, g3, g4, g5, g6, g7;
  bf16x8 af0, af1, af2, af3;
  f32x4 acc[4][8];

  #define LOAD8(ROFF, KT)                                                    \
    {                                                                        \
      const float* p = hb + (size_t)(ROFF) * NU + (KT) * 32;                 \
      g0 = *reinterpret_cast<const float4*>(p);                              \
      g1 = *reinterpret_cast<const float4*>(p + 4);                          \
      g2 = *reinterpret_cast<const float4*>(p + 16 * NU);                    \
      g3 = *reinterpret_cast<const float4*>(p + 16 * NU + 4);                \
      g4 = *reinterpret_cast<const float4*>(p + 32 * NU);                    \
      g5 = *reinterpret_cast<const float4*>(p + 32 * NU + 4);                \
      g6 = *reinterpret_cast<const float4*>(p + 48 * NU);                    \
      g7 = *reinterpret_cast<const float4*>(p + 48 * NU + 4);                \
    }

  #define CVT                                                                \
    {                                                                        \
      uint4 u;                                                               \
      u.x = pk2(g0.x, g0.y); u.y = pk2(g0.z, g0.w);                          \
      u.z = pk2(g1.x, g1.y); u.w = pk2(g1.z, g1.w);                          \
      af0 = *reinterpret_cast<bf16x8*>(&u);                                  \
      u.x = pk2(g2.x, g2.y); u.y = pk2(g2.z, g2.w);                          \
      u.z = pk2(g3.x, g3.y); u.w = pk2(g3.z, g3.w);                          \
      af1 = *reinterpret_cast<bf16x8*>(&u);                                  \
      u.x = pk2(g4.x, g4.y); u.y = pk2(g4.z, g4.w);                          \
      u.z = pk2(g5.x, g5.y); u.w = pk2(g5.z, g5.w);                          \
      af2 = *reinterpret_cast<bf16x8*>(&u);                                  \
      u.x = pk2(g6.x, g6.y); u.y = pk2(g6.z, g6.w);                          \
      u.z = pk2(g7.x, g7.y); u.w = pk2(g7.z, g7.w);                          \
      af3 = *reinterpret_cast<bf16x8*>(&u);                                  \
    }

  #define STEP(KT)                                                           \
    {                                                                        \
      const int kofs = (((KT) * 64 + lg * 16) ^ swz);                        \
      bf16x8 bfr[8];                                                         \
      _Pragma("unroll")                                                      \
      for (int cc = 0; cc < 8; ++cc)                                         \
        bfr[cc] = *reinterpret_cast<const bf16x8*>(wbytes + (cc * 16 + lr) * 1024 + kofs); \
      _Pragma("unroll")                                                      \
      for (int cc = 0; cc < 8; ++cc) {                                       \
        acc[0][cc] = __builtin_amdgcn_mfma_f32_16x16x32_bf16(af0, bfr[cc], acc[0][cc], 0, 0, 0); \
        acc[1][cc] = __builtin_amdgcn_mfma_f32_16x16x32_bf16(af1, bfr[cc], acc[1][cc], 0, 0, 0); \
        acc[2][cc] = __builtin_amdgcn_mfma_f32_16x16x32_bf16(af2, bfr[cc], acc[2][cc], 0, 0, 0); \
        acc[3][cc] = __builtin_amdgcn_mfma_f32_16x16x32_bf16(af3, bfr[cc], acc[3][cc], 0, 0, 0); \
      }                                                                      \
    }

  #define ZERO_ACC                                                           \
    _Pragma("unroll")                                                        \
    for (int rc = 0; rc < 4; ++rc)                                           \
      _Pragma("unroll")                                                      \
      for (int cc = 0; cc < 8; ++cc)                                         \
        acc[rc][cc] = (f32x4){0.f, 0.f, 0.f, 0.f};

  #define EPI(PROW)                                                          \
    {                                                                        \
      float fvl[8], vvl[8];                                                  \
      _Pragma("unroll")                                                      \
      for (int cc = 0; cc < 8; ++cc) {                                       \
        int col = cg * 128 + cc * 16 + lr;                                   \
        fvl[cc] = first[b0 * NU + col];                                      \
        vvl[cc] = V[col];                                                    \
      }                                                                      \
      _Pragma("unroll")                                                      \
      for (int rc = 0; rc < 4; ++rc) {                                       \
        f32x4 pr;                                                            \
        _Pragma("unroll")                                                    \
        for (int r = 0; r < 4; ++r) {                                        \
          float s = 0.f;                                                     \
          _Pragma("unroll")                                                  \
          for (int cc = 0; cc < 8; ++cc)                                     \
            s += vvl[cc] * fast_tanh(fvl[cc] + acc[rc][cc][r]);              \
          pr[r] = s;                                                         \
        }                                                                    \
        _Pragma("unroll")                                                    \
        for (int m = 1; m < 16; m <<= 1) {                                   \
          _Pragma("unroll")                                                  \
          for (int r = 0; r < 4; ++r) pr[r] += __shfl_xor(pr[r], m, 64);     \
        }                                                                    \
        if (lr == 0) {                                                       \
          _Pragma("unroll")                                                  \
          for (int r = 0; r < 4; ++r)                                        \
            atomicAdd(&s0[(PROW) + rc * 16 + lg * 4 + r], pr[r]);            \
        }                                                                    \
      }                                                                      \
    }

  // ---- prologue
  LOAD8(0, 0);

  // ---- panel 0 (rows prow0 .. +64)
  ZERO_ACC;
  #pragma unroll 1
  for (int kt = 0; kt < 16; ++kt) {
    CVT;                               // consumes g (one waitcnt for all 8)
    if (kt < 15) { LOAD8(0, kt + 1); } // re-issue slots for kt+1
    else         { LOAD8(64, 0); }     // prefetch panel 1, kt 0
    STEP(kt);
  }
  EPI(prow0);                          // runs while panel-1 loads are in flight

  // ---- panel 1 (rows prow0+64 .. +128)
  ZERO_ACC;
  #pragma unroll 1
  for (int kt = 0; kt < 16; ++kt) {
    CVT;
    if (kt < 15) { LOAD8(64, kt + 1); }
    STEP(kt);
  }
  EPI(prow0 + 64);

  #undef LOAD8
  #undef CVT
  #undef STEP
  #undef ZERO_ACC
  #undef EPI
}

// ---------- softmax over S per batch (in-place in d_out) + context ----------
__global__ __launch_bounds__(256) void softmax_ctx(const float* __restrict__ sp,
                                                   float* __restrict__ out) {
  const int b = blockIdx.x;
  const int t = threadIdx.x;
  float* wgt = out + NBATCH * NU + (size_t)b * SEQ;
  __shared__ float red[4];

  float v[8];
  float mx = -1e30f;
  #pragma unroll
  for (int i = 0; i < 8; ++i) { v[i] = wgt[t + i * 256]; mx = fmaxf(mx, v[i]); }
  #pragma unroll
  for (int m = 1; m < 64; m <<= 1) mx = fmaxf(mx, __shfl_xor(mx, m, 64));
  if ((t & 63) == 0) red[t >> 6] = mx;
  __syncthreads();
  mx = fmaxf(fmaxf(red[0], red[1]), fmaxf(red[2], red[3]));
  __syncthreads();

  float se = 0.f;
  #pragma unroll
  for (int i = 0; i < 8; ++i) { v[i] = __expf(v[i] - mx); se += v[i]; }
  #pragma unroll
  for (int m = 1; m < 64; m <<= 1) se += __shfl_xor(se, m, 64);
  if ((t & 63) == 0) red[t >> 6] = se;
  __syncthreads();
  se = red[0] + red[1] + red[2] + red[3];
  __syncthreads();

  const float inv = 1.0f / se;
  float sw = 0.f;
  #pragma unroll
  for (int i = 0; i < 8; ++i) { float wi = v[i] * inv; wgt[t + i * 256] = wi; sw += wi; }
  #pragma unroll
  for (int m = 1; m < 64; m <<= 1) sw += __shfl_xor(sw, m, 64);
  if ((t & 63) == 0) red[t >> 6] = sw;
  __syncthreads();
  sw = red[0] + red[1] + red[2] + red[3];

  out[b * NU + t]       = sp[b * NU + t] * sw;
  out[b * NU + t + 256] = sp[b * NU + t + 256] * sw;
}

extern "C" void kernel_launch(void* const* d_in, const int* in_sizes, int n_in,
                              void* d_out, int out_size, void* d_ws, size_t ws_size,
                              hipStream_t stream) {
  (void)in_sizes; (void)n_in; (void)out_size; (void)ws_size;
  const float* s_prev = (const float*)d_in[0];
  const float* h      = (const float*)d_in[1];
  const float* Wk     = (const float*)d_in[2];
  const float* Wb     = (const float*)d_in[3];
  const float* Uk     = (const float*)d_in[4];
  const float* Ub     = (const float*)d_in[5];
  const float* Vk     = (const float*)d_in[6];
  // d_in[7] = V_bias: softmax-shift-invariant, does not affect outputs.

  float* out   = (float*)d_out;
  float* first = (float*)d_ws;                    // 64 KB
  short* WtSw  = (short*)((char*)d_ws + 65536);   // 512 KB
  float* s0    = out + NBATCH * NU;               // score accumulator in weights slot

  hipMemsetAsync(s0, 0, (size_t)NBATCH * SEQ * sizeof(float), stream);
  prep_all   <<<1088, 256, 0, stream>>>(Wk, s_prev, Uk, Ub, Wb, WtSw, first);
  attn_main  <<< 256, 512, 0, stream>>>(h, WtSw, first, Vk, s0);
  softmax_ctx<<<  32, 256, 0, stream>>>(s_prev, out);
}

// Round 11
// 206.598 us; speedup vs baseline: 1.2368x; 1.2368x over previous
//
#include <hip/hip_runtime.h>

#define NBATCH 32
#define SEQ    2048
#define NU     512

typedef __attribute__((ext_vector_type(8))) short bf16x8;
typedef __attribute__((ext_vector_type(4))) float f32x4;

__device__ __forceinline__ short bf16_rne(float f) {
  union { float f; unsigned u; } v; v.f = f;
  unsigned r = v.u + 0x7fffu + ((v.u >> 16) & 1u);
  return (short)(r >> 16);
}

// pack bf16(lo), bf16(hi) (truncation) into one u32 via a single v_perm_b32
__device__ __forceinline__ unsigned pk2(float lo, float hi) {
  return __builtin_amdgcn_perm(__float_as_uint(hi), __float_as_uint(lo), 0x07060302u);
}

__device__ __forceinline__ float fast_tanh(float x) {
  float ax = __builtin_fabsf(x);
  float t  = __expf(-2.0f * ax);
  float r  = (1.0f - t) / (1.0f + t);
  return x < 0.0f ? -r : r;
}

// ---------- fused prep ----------
// blocks 0..1023: WtSw[col*512 + j] = bf16(W[j ^ ((col&7)<<3)][col])
// blocks 1024..1087: first[b][u] = s_prev[b]@U + U_bias + W_bias
__global__ __launch_bounds__(256) void prep_all(const float* __restrict__ W,
                                                const float* __restrict__ sp,
                                                const float* __restrict__ U,
                                                const float* __restrict__ Ub,
                                                const float* __restrict__ Wb,
                                                short* __restrict__ WtSw,
                                                float* __restrict__ first) {
  __shared__ float srow[NU];
  if (blockIdx.x < 1024) {
    int idx = blockIdx.x * 256 + threadIdx.x;
    int col = idx >> 9, j = idx & 511;
    int ksrc = j ^ ((col & 7) << 3);
    WtSw[idx] = bf16_rne(W[(size_t)ksrc * NU + col]);
  } else {
    int blk = blockIdx.x - 1024;
    int b = blk >> 1, half = blk & 1, t = threadIdx.x;
    srow[t]       = sp[b * NU + t];
    srow[t + 256] = sp[b * NU + t + 256];
    __syncthreads();
    int col = half * 256 + t;
    float acc = Ub[col] + Wb[col];
    #pragma unroll 8
    for (int k = 0; k < NU; ++k) acc += srow[k] * U[(size_t)k * NU + col];
    first[b * NU + col] = acc;
  }
}

// ---------- main: W-stationary LDS, barrier-free, deep-pipelined, 64x64 wave tile ----------
// Grid 256 (4 cg x 64 blk; XCD = blk%8 shared by the 4 cgs -> h L2-local, proven R9).
// Block: 512 thr = 8 waves = 4 panel-slots x 2 col-halves. Wave = 64 rows x 64 cols,
// acc[4][4] f32x4 = 64 f32 (AGPR). Each wave chains 4 panels; per kt: CVT (consumes
// g0..g7) -> issue 8 loads for kt+1 -> 4 ds_read_b128 + 16 MFMA. Fully unrolled.
__global__ __launch_bounds__(512, 2) void attn_main(
    const float* __restrict__ h,      // (65536, 512) fp32
    const short* __restrict__ WtSw,   // pre-swizzled (512 cols x 512 k) bf16
    const float* __restrict__ first,  // (B, 512) incl. U_bias + W_bias
    const float* __restrict__ V,      // (512)
    float* __restrict__ s0)           // (65536) score accumulator (pre-zeroed)
{
  __shared__ short Wlds[128 * NU];    // 128 KB

  const int tid  = threadIdx.x;
  const int lane = tid & 63;
  const int w    = tid >> 6;          // 0..7
  const int s    = w >> 1;            // panel slot 0..3
  const int hf   = w & 1;             // col half 0..1
  const int lr   = lane & 15, lg = lane >> 4;

  const int bid = blockIdx.x;
  const int cg  = bid >> 6;           // 128-col group (0..3)
  const int blk = bid & 63;           // 1024-row block; XCD = blk%8

  // ---- stage the block's W slice once (linear copy, coalesced)
  {
    const short* src = WtSw + (size_t)cg * 128 * NU;
    #pragma unroll
    for (int i = 0; i < 16; ++i) {
      int o = i * 4096 + tid * 8;
      *reinterpret_cast<uint4*>(&Wlds[o]) = *reinterpret_cast<const uint4*>(src + o);
    }
  }
  __syncthreads();

  const int swz = (lr & 7) << 4;      // byte XOR within a W row (matches prep)
  const char* wbytes = reinterpret_cast<const char*>(Wlds);
  const int b0 = blk >> 1;            // batch

  // wave's panel pi (0..3): rows base_row + pi*256 .. +64
  const int base_row = blk * 1024 + s * 64;
  const float* hb = h + (size_t)(base_row + lr) * NU + lg * 8;

  float4 g0, g1, g2, g3, g4, g5, g6, g7;
  bf16x8 af0, af1, af2, af3;
  f32x4 acc[4][4];

  #define LOAD8(PI, KT)                                                      \
    {                                                                        \
      const float* p = hb + (size_t)(PI) * 256 * NU + (KT) * 32;             \
      g0 = *reinterpret_cast<const float4*>(p);                              \
      g1 = *reinterpret_cast<const float4*>(p + 4);                          \
      g2 = *reinterpret_cast<const float4*>(p + 16 * NU);                    \
      g3 = *reinterpret_cast<const float4*>(p + 16 * NU + 4);                \
      g4 = *reinterpret_cast<const float4*>(p + 32 * NU);                    \
      g5 = *reinterpret_cast<const float4*>(p + 32 * NU + 4);                \
      g6 = *reinterpret_cast<const float4*>(p + 48 * NU);                    \
      g7 = *reinterpret_cast<const float4*>(p + 48 * NU + 4);                \
    }

  #define CVT                                                                \
    {                                                                        \
      uint4 u;                                                               \
      u.x = pk2(g0.x, g0.y); u.y = pk2(g0.z, g0.w);                          \
      u.z = pk2(g1.x, g1.y); u.w = pk2(g1.z, g1.w);                          \
      af0 = *reinterpret_cast<bf16x8*>(&u);                                  \
      u.x = pk2(g2.x, g2.y); u.y = pk2(g2.z, g2.w);                          \
      u.z = pk2(g3.x, g3.y); u.w = pk2(g3.z, g3.w);                          \
      af1 = *reinterpret_cast<bf16x8*>(&u);                                  \
      u.x = pk2(g4.x, g4.y); u.y = pk2(g4.z, g4.w);                          \
      u.z = pk2(g5.x, g5.y); u.w = pk2(g5.z, g5.w);                          \
      af2 = *reinterpret_cast<bf16x8*>(&u);                                  \
      u.x = pk2(g6.x, g6.y); u.y = pk2(g6.z, g6.w);                          \
      u.z = pk2(g7.x, g7.y); u.w = pk2(g7.z, g7.w);                          \
      af3 = *reinterpret_cast<bf16x8*>(&u);                                  \
    }

  #define STEP(KT)                                                           \
    {                                                                        \
      const int kofs = (((KT) * 64 + lg * 16) ^ swz);                        \
      bf16x8 bfr[4];                                                         \
      _Pragma("unroll")                                                      \
      for (int cc = 0; cc < 4; ++cc)                                         \
        bfr[cc] = *reinterpret_cast<const bf16x8*>(                          \
            wbytes + (hf * 64 + cc * 16 + lr) * 1024 + kofs);                \
      _Pragma("unroll")                                                      \
      for (int cc = 0; cc < 4; ++cc) {                                       \
        acc[0][cc] = __builtin_amdgcn_mfma_f32_16x16x32_bf16(af0, bfr[cc], acc[0][cc], 0, 0, 0); \
        acc[1][cc] = __builtin_amdgcn_mfma_f32_16x16x32_bf16(af1, bfr[cc], acc[1][cc], 0, 0, 0); \
        acc[2][cc] = __builtin_amdgcn_mfma_f32_16x16x32_bf16(af2, bfr[cc], acc[2][cc], 0, 0, 0); \
        acc[3][cc] = __builtin_amdgcn_mfma_f32_16x16x32_bf16(af3, bfr[cc], acc[3][cc], 0, 0, 0); \
      }                                                                      \
    }

  // prologue: panel 0, kt 0
  LOAD8(0, 0);

  #pragma unroll 1
  for (int pi = 0; pi < 4; ++pi) {
    #pragma unroll
    for (int rc = 0; rc < 4; ++rc)
      #pragma unroll
      for (int cc = 0; cc < 4; ++cc)
        acc[rc][cc] = (f32x4){0.f, 0.f, 0.f, 0.f};

    #pragma unroll
    for (int kt = 0; kt < 16; ++kt) {
      CVT;                                  // consumes g (one waitcnt)
      if (kt < 15) LOAD8(pi, kt + 1);       // re-issue slots for next kt
      STEP(kt);
    }
    if (pi < 3) LOAD8(pi + 1, 0);           // panel-boundary prefetch (flies during EPI)

    // ---- epilogue: tanh + V, reduce over this wave's 64 cols, atomic add
    {
      const int prow = base_row + pi * 256;
      float fvl[4], vvl[4];
      #pragma unroll
      for (int cc = 0; cc < 4; ++cc) {
        int col = cg * 128 + hf * 64 + cc * 16 + lr;
        fvl[cc] = first[b0 * NU + col];
        vvl[cc] = V[col];
      }
      #pragma unroll
      for (int rc = 0; rc < 4; ++rc) {
        f32x4 pr;
        #pragma unroll
        for (int r = 0; r < 4; ++r) {
          float sacc = 0.f;
          #pragma unroll
          for (int cc = 0; cc < 4; ++cc)
            sacc += vvl[cc] * fast_tanh(fvl[cc] + acc[rc][cc][r]);
          pr[r] = sacc;
        }
        #pragma unroll
        for (int m = 1; m < 16; m <<= 1) {
          #pragma unroll
          for (int r = 0; r < 4; ++r) pr[r] += __shfl_xor(pr[r], m, 64);
        }
        if (lr == 0) {
          #pragma unroll
          for (int r = 0; r < 4; ++r)
            atomicAdd(&s0[prow + rc * 16 + lg * 4 + r], pr[r]);
        }
      }
    }
  }

  #undef LOAD8
  #undef CVT
  #undef STEP
}

// ---------- softmax over S per batch (in-place in d_out) + context ----------
__global__ __launch_bounds__(256) void softmax_ctx(const float* __restrict__ sp,
                                                   float* __restrict__ out) {
  const int b = blockIdx.x;
  const int t = threadIdx.x;
  float* wgt = out + NBATCH * NU + (size_t)b * SEQ;
  __shared__ float red[4];

  float v[8];
  float mx = -1e30f;
  #pragma unroll
  for (int i = 0; i < 8; ++i) { v[i] = wgt[t + i * 256]; mx = fmaxf(mx, v[i]); }
  #pragma unroll
  for (int m = 1; m < 64; m <<= 1) mx = fmaxf(mx, __shfl_xor(mx, m, 64));
  if ((t & 63) == 0) red[t >> 6] = mx;
  __syncthreads();
  mx = fmaxf(fmaxf(red[0], red[1]), fmaxf(red[2], red[3]));
  __syncthreads();

  float se = 0.f;
  #pragma unroll
  for (int i = 0; i < 8; ++i) { v[i] = __expf(v[i] - mx); se += v[i]; }
  #pragma unroll
  for (int m = 1; m < 64; m <<= 1) se += __shfl_xor(se, m, 64);
  if ((t & 63) == 0) red[t >> 6] = se;
  __syncthreads();
  se = red[0] + red[1] + red[2] + red[3];
  __syncthreads();

  const float inv = 1.0f / se;
  float sw = 0.f;
  #pragma unroll
  for (int i = 0; i < 8; ++i) { float wi = v[i] * inv; wgt[t + i * 256] = wi; sw += wi; }
  #pragma unroll
  for (int m = 1; m < 64; m <<= 1) sw += __shfl_xor(sw, m, 64);
  if ((t & 63) == 0) red[t >> 6] = sw;
  __syncthreads();
  sw = red[0] + red[1] + red[2] + red[3];

  out[b * NU + t]       = sp[b * NU + t] * sw;
  out[b * NU + t + 256] = sp[b * NU + t + 256] * sw;
}

extern "C" void kernel_launch(void* const* d_in, const int* in_sizes, int n_in,
                              void* d_out, int out_size, void* d_ws, size_t ws_size,
                              hipStream_t stream) {
  (void)in_sizes; (void)n_in; (void)out_size; (void)ws_size;
  const float* s_prev = (const float*)d_in[0];
  const float* h      = (const float*)d_in[1];
  const float* Wk     = (const float*)d_in[2];
  const float* Wb     = (const float*)d_in[3];
  const float* Uk     = (const float*)d_in[4];
  const float* Ub     = (const float*)d_in[5];
  const float* Vk     = (const float*)d_in[6];
  // d_in[7] = V_bias: softmax-shift-invariant, does not affect outputs.

  float* out   = (float*)d_out;
  float* first = (float*)d_ws;                    // 64 KB
  short* WtSw  = (short*)((char*)d_ws + 65536);   // 512 KB
  float* s0    = out + NBATCH * NU;               // score accumulator in weights slot

  hipMemsetAsync(s0, 0, (size_t)NBATCH * SEQ * sizeof(float), stream);
  prep_all   <<<1088, 256, 0, stream>>>(Wk, s_prev, Uk, Ub, Wb, WtSw, first);
  attn_main  <<< 256, 512, 0, stream>>>(h, WtSw, first, Vk, s0);
  softmax_ctx<<<  32, 256, 0, stream>>>(s_prev, out);
}

// Round 12
// 110.526 us; speedup vs baseline: 2.3119x; 1.8692x over previous
//
#include <hip/hip_runtime.h>

#define NBATCH 32
#define SEQ    2048
#define NU     512
#define ASTR   36   // LDS row stride in shorts (72 B)

typedef __attribute__((ext_vector_type(8)))  short bf16x8;
typedef __attribute__((ext_vector_type(16))) float f32x16;

__device__ __forceinline__ short bf16_rne(float f) {
  union { float f; unsigned u; } v; v.f = f;
  unsigned r = v.u + 0x7fffu + ((v.u >> 16) & 1u);
  return (short)(r >> 16);
}

// pack bf16(lo), bf16(hi) (truncation) into one u32 via a single v_perm_b32
__device__ __forceinline__ unsigned pk2(float lo, float hi) {
  return __builtin_amdgcn_perm(__float_as_uint(hi), __float_as_uint(lo), 0x07060302u);
}

__device__ __forceinline__ float fast_tanh(float x) {
  float ax = __builtin_fabsf(x);
  float t  = __expf(-2.0f * ax);
  float r  = (1.0f - t) / (1.0f + t);
  return x < 0.0f ? -r : r;
}

// ---------- fused prep ----------
// blocks 0..1023: Wt[col*512 + k] = bf16(W[k*512 + col]) (plain transpose)
// blocks 1024..1087: first[b][u] = s_prev[b]@U + U_bias + W_bias
__global__ __launch_bounds__(256) void prep_all(const float* __restrict__ W,
                                                const float* __restrict__ sp,
                                                const float* __restrict__ U,
                                                const float* __restrict__ Ub,
                                                const float* __restrict__ Wb,
                                                short* __restrict__ Wt,
                                                float* __restrict__ first) {
  __shared__ float srow[NU];
  if (blockIdx.x < 1024) {
    int idx = blockIdx.x * 256 + threadIdx.x;
    int u = idx >> 9, k = idx & 511;
    Wt[(size_t)u * NU + k] = bf16_rne(W[(size_t)k * NU + u]);
  } else {
    int blk = blockIdx.x - 1024;
    int b = blk >> 1, half = blk & 1, t = threadIdx.x;
    srow[t]       = sp[b * NU + t];
    srow[t + 256] = sp[b * NU + t + 256];
    __syncthreads();
    int col = half * 256 + t;
    float acc = Ub[col] + Wb[col];
    #pragma unroll 8
    for (int k = 0; k < NU; ++k) acc += srow[k] * U[(size_t)k * NU + col];
    first[b * NU + col] = acc;
  }
}

// ---------- main: 256 rows x 128 cols per block (R4 structure x2 rows) ----------
// 8 waves as 4 row-slots x 2 col-slots, wave tile 64x64 via 32x32x16 MFMA
// (acc[2][2] f32x16 = 64 f32). Depth-2 h prefetch, dbuf LDS, 16 barriers.
__global__ __launch_bounds__(512, 4) void attn_main(
    const float* __restrict__ h,      // (65536, 512) fp32
    const short* __restrict__ Wt,     // (512 cols x 512 k) bf16
    const float* __restrict__ first,  // (B, 512) incl. U_bias + W_bias
    const float* __restrict__ V,      // (512)
    float* __restrict__ s0)           // (65536) score accumulator (pre-zeroed)
{
  __shared__ short Alds[2][256 * ASTR];   // 18.4 KB each
  __shared__ short Blds[2][128 * ASTR];   //  9.2 KB each
  __shared__ float scores_lds[256];

  const int tid  = threadIdx.x;
  const int lane = tid & 63;
  const int w    = tid >> 6;
  const int wr   = w >> 1, wc = w & 1;
  const int l31  = lane & 31, hi = lane >> 5;

  // XCD-aware remap (R4-proven): 4 col-quarters of a row-panel adjacent on one XCD
  const int bid = blockIdx.x;
  const int lb  = (bid & 7) * 128 + (bid >> 3);    // grid 1024 = 8*128, bijective
  const int panel = lb >> 2, q = lb & 3;           // 256 panels x 4 col-quarters
  const int rowbase = panel * 256;
  const int b = panel >> 3;                        // 8 panels per batch

  // staging addresses
  const int arow  = tid >> 1;                      // 0..255
  const int ahalf = tid & 1;
  const float* hA = h + (size_t)(rowbase + arow) * NU + ahalf * 16;
  const int awr   = arow * ASTR + ahalf * 16;
  const short* bsrc = Wt + (size_t)(q * 128 + (tid >> 2)) * NU + (tid & 3) * 8;
  const int bwr   = (tid >> 2) * ASTR + (tid & 3) * 8;

  // compute-read bases (shorts)
  const int rA0 = (wr * 64 + l31) * ASTR + hi * 8;
  const int rA1 = rA0 + 32 * ASTR;
  const int rB0 = (wc * 64 + l31) * ASTR + hi * 8;
  const int rB1 = rB0 + 32 * ASTR;

  f32x16 acc[2][2];
  #pragma unroll
  for (int rt = 0; rt < 2; ++rt)
    #pragma unroll
    for (int ct = 0; ct < 2; ++ct)
      #pragma unroll
      for (int r = 0; r < 16; ++r) acc[rt][ct][r] = 0.f;

  float4 ha0, ha1, ha2, ha3;   // h slot 0
  float4 hb0, hb1, hb2, hb3;   // h slot 1
  int4   bq0;                  // B tile in flight

  #define LOAD_H(V0, V1, V2, V3, ktn)                                       \
    {                                                                       \
      const float* p = hA + (ktn) * 32;                                     \
      V0 = *reinterpret_cast<const float4*>(p + 0);                         \
      V1 = *reinterpret_cast<const float4*>(p + 4);                         \
      V2 = *reinterpret_cast<const float4*>(p + 8);                         \
      V3 = *reinterpret_cast<const float4*>(p + 12);                        \
    }

  #define CVT_WRITE(dst, V0, V1, V2, V3)                                    \
    {                                                                       \
      uint4 u0, u1;                                                         \
      u0.x = pk2(V0.x, V0.y); u0.y = pk2(V0.z, V0.w);                       \
      u0.z = pk2(V1.x, V1.y); u0.w = pk2(V1.z, V1.w);                       \
      u1.x = pk2(V2.x, V2.y); u1.y = pk2(V2.z, V2.w);                       \
      u1.z = pk2(V3.x, V3.y); u1.w = pk2(V3.z, V3.w);                       \
      *reinterpret_cast<uint4*>(&Alds[dst][awr])     = u0;                  \
      *reinterpret_cast<uint4*>(&Alds[dst][awr + 8]) = u1;                  \
      *reinterpret_cast<int4*>(&Blds[dst][bwr])      = bq0;                 \
    }

  #define COMPUTE(cur)                                                      \
    _Pragma("unroll")                                                       \
    for (int ks = 0; ks < 2; ++ks) {                                        \
      bf16x8 af0, af1, bf0, bf1;                                            \
      af0 = *reinterpret_cast<const bf16x8*>(&Alds[cur][rA0 + ks * 16]);    \
      af1 = *reinterpret_cast<const bf16x8*>(&Alds[cur][rA1 + ks * 16]);    \
      bf0 = *reinterpret_cast<const bf16x8*>(&Blds[cur][rB0 + ks * 16]);    \
      bf1 = *reinterpret_cast<const bf16x8*>(&Blds[cur][rB1 + ks * 16]);    \
      acc[0][0] = __builtin_amdgcn_mfma_f32_32x32x16_bf16(af0, bf0, acc[0][0], 0, 0, 0); \
      acc[0][1] = __builtin_amdgcn_mfma_f32_32x32x16_bf16(af0, bf1, acc[0][1], 0, 0, 0); \
      acc[1][0] = __builtin_amdgcn_mfma_f32_32x32x16_bf16(af1, bf0, acc[1][0], 0, 0, 0); \
      acc[1][1] = __builtin_amdgcn_mfma_f32_32x32x16_bf16(af1, bf1, acc[1][1], 0, 0, 0); \
    }

  // ---- prologue: stage k-tile 0 into buf 0; h(1) in flight
  bq0 = *reinterpret_cast<const int4*>(bsrc);
  LOAD_H(ha0, ha1, ha2, ha3, 0);
  CVT_WRITE(0, ha0, ha1, ha2, ha3);
  LOAD_H(hb0, hb1, hb2, hb3, 1);
  __syncthreads();

  // ---- main loop: kt = 0..13 in pairs
  #pragma unroll 1
  for (int kt2 = 0; kt2 < 7; ++kt2) {
    const int kt = kt2 * 2;
    // even kt: compute buf0; issue B(kt+1), h(kt+2); cvt h(kt+1)+B(kt+1) -> buf1
    bq0 = *reinterpret_cast<const int4*>(bsrc + (kt + 1) * 32);
    LOAD_H(ha0, ha1, ha2, ha3, kt + 2);
    COMPUTE(0);
    CVT_WRITE(1, hb0, hb1, hb2, hb3);
    __syncthreads();
    // odd kt+1: compute buf1; issue B(kt+2), h(kt+3); cvt h(kt+2)+B(kt+2) -> buf0
    bq0 = *reinterpret_cast<const int4*>(bsrc + (kt + 2) * 32);
    LOAD_H(hb0, hb1, hb2, hb3, kt + 3);
    COMPUTE(1);
    CVT_WRITE(0, ha0, ha1, ha2, ha3);
    __syncthreads();
  }

  // kt = 14: compute buf0; issue B(15); cvt h(15)+B(15) -> buf1
  bq0 = *reinterpret_cast<const int4*>(bsrc + 15 * 32);
  COMPUTE(0);
  CVT_WRITE(1, hb0, hb1, hb2, hb3);
  __syncthreads();

  // kt = 15: compute only
  COMPUTE(1);

  #undef LOAD_H
  #undef CVT_WRITE
  #undef COMPUTE

  // ---- epilogue: tanh + V, reduce over this block's 128 cols -> per-row partials
  float fv[2], vv[2];
  #pragma unroll
  for (int ct = 0; ct < 2; ++ct) {
    int col = q * 128 + wc * 64 + ct * 32 + l31;
    fv[ct] = first[b * NU + col];
    vv[ct] = V[col];
  }
  float part[2][16];
  #pragma unroll
  for (int rt = 0; rt < 2; ++rt) {
    #pragma unroll
    for (int r = 0; r < 16; ++r) {
      float p = 0.f;
      #pragma unroll
      for (int ct = 0; ct < 2; ++ct)
        p += vv[ct] * fast_tanh(fv[ct] + acc[rt][ct][r]);
      #pragma unroll
      for (int m = 1; m < 32; m <<= 1) p += __shfl_xor(p, m, 64);
      part[rt][r] = p;
    }
  }
  __syncthreads();
  if (wc == 0 && l31 == 0) {
    #pragma unroll
    for (int rt = 0; rt < 2; ++rt)
      #pragma unroll
      for (int r = 0; r < 16; ++r)
        scores_lds[wr * 64 + rt * 32 + (r & 3) + 8 * (r >> 2) + 4 * hi] = part[rt][r];
  }
  __syncthreads();
  if (wc == 1 && l31 == 0) {
    #pragma unroll
    for (int rt = 0; rt < 2; ++rt)
      #pragma unroll
      for (int r = 0; r < 16; ++r)
        scores_lds[wr * 64 + rt * 32 + (r & 3) + 8 * (r >> 2) + 4 * hi] += part[rt][r];
  }
  __syncthreads();
  if (tid < 256) atomicAdd(&s0[rowbase + tid], scores_lds[tid]);
}

// ---------- softmax over S per batch (in-place in d_out) + context ----------
__global__ __launch_bounds__(256) void softmax_ctx(const float* __restrict__ sp,
                                                   float* __restrict__ out) {
  const int b = blockIdx.x;
  const int t = threadIdx.x;
  float* wgt = out + NBATCH * NU + (size_t)b * SEQ;
  __shared__ float red[4];

  float v[8];
  float mx = -1e30f;
  #pragma unroll
  for (int i = 0; i < 8; ++i) { v[i] = wgt[t + i * 256]; mx = fmaxf(mx, v[i]); }
  #pragma unroll
  for (int m = 1; m < 64; m <<= 1) mx = fmaxf(mx, __shfl_xor(mx, m, 64));
  if ((t & 63) == 0) red[t >> 6] = mx;
  __syncthreads();
  mx = fmaxf(fmaxf(red[0], red[1]), fmaxf(red[2], red[3]));
  __syncthreads();

  float se = 0.f;
  #pragma unroll
  for (int i = 0; i < 8; ++i) { v[i] = __expf(v[i] - mx); se += v[i]; }
  #pragma unroll
  for (int m = 1; m < 64; m <<= 1) se += __shfl_xor(se, m, 64);
  if ((t & 63) == 0) red[t >> 6] = se;
  __syncthreads();
  se = red[0] + red[1] + red[2] + red[3];
  __syncthreads();

  const float inv = 1.0f / se;
  float sw = 0.f;
  #pragma unroll
  for (int i = 0; i < 8; ++i) { float wi = v[i] * inv; wgt[t + i * 256] = wi; sw += wi; }
  #pragma unroll
  for (int m = 1; m < 64; m <<= 1) sw += __shfl_xor(sw, m, 64);
  if ((t & 63) == 0) red[t >> 6] = sw;
  __syncthreads();
  sw = red[0] + red[1] + red[2] + red[3];

  out[b * NU + t]       = sp[b * NU + t] * sw;
  out[b * NU + t + 256] = sp[b * NU + t + 256] * sw;
}

extern "C" void kernel_launch(void* const* d_in, const int* in_sizes, int n_in,
                              void* d_out, int out_size, void* d_ws, size_t ws_size,
                              hipStream_t stream) {
  (void)in_sizes; (void)n_in; (void)out_size; (void)ws_size;
  const float* s_prev = (const float*)d_in[0];
  const float* h      = (const float*)d_in[1];
  const float* Wk     = (const float*)d_in[2];
  const float* Wb     = (const float*)d_in[3];
  const float* Uk     = (const float*)d_in[4];
  const float* Ub     = (const float*)d_in[5];
  const float* Vk     = (const float*)d_in[6];
  // d_in[7] = V_bias: softmax-shift-invariant, does not affect outputs.

  float* out   = (float*)d_out;
  float* first = (float*)d_ws;                    // 64 KB
  short* Wt    = (short*)((char*)d_ws + 65536);   // 512 KB
  float* s0    = out + NBATCH * NU;               // score accumulator in weights slot

  hipMemsetAsync(s0, 0, (size_t)NBATCH * SEQ * sizeof(float), stream);
  prep_all   <<<1088, 256, 0, stream>>>(Wk, s_prev, Uk, Ub, Wb, Wt, first);
  attn_main  <<<1024, 512, 0, stream>>>(h, Wt, first, Vk, s0);
  softmax_ctx<<<  32, 256, 0, stream>>>(s_prev, out);
}